// Round 4
// baseline (254.751 us; speedup 1.0000x reference)
//
#include <hip/hip_runtime.h>
#include <math.h>

#define NB 4096
#define NS 50
#define NH 64
#define NITEM 40000
#define ROW4 (NITEM / 4)  // 10000 float4 per row

typedef float f4 __attribute__((ext_vector_type(4)));

// One block (256 threads, 4 waves) per batch row b. 4096 blocks at ~110 VGPR
// -> 4 blocks/CU resident -> 4 generations, so later blocks' compute overlaps
// earlier blocks' store drain (the fix for round 3's single-generation
// serialization).
//
// Phase order (the fix for round 2's convoy): the only __syncthreads that
// sits behind a long store queue is the mandatory drain before the scatter.
//   1. waves 0..3 split s (s = warp, warp+4, ...): lane i owns output-dim i,
//      Ur[i,:] in 64 VGPRs, all_memory row addresses wave-uniform.
//      lane 0 of each reduce writes sLDS[s].
//   2. __syncthreads (drains only ~50 small input loads — cheap).
//   3. wave 0: 50-wide softmax -> pLDS   (runs WHILE waves 1-3 issue stores)
//      all waves: zero own row, plain float4 stores (L2-allocating).
//   4. __syncthreads (the store drain — this IS the BW-bound work).
//   5. wave 0 lanes 0..49: atomicAdd probs onto own freshly-zeroed row.
//      Duplicate items accumulate exactly like the reference's .at[].add.
__global__ __launch_bounds__(256) void fused_row(
    const float* __restrict__ all_memory,   // [NB, NS, NH]
    const float* __restrict__ last_memory,  // [NB, NH]
    const float* __restrict__ Wr,           // [NH, NH]
    const float* __restrict__ Ur,           // [NH, NH]
    const float* __restrict__ Vr_w,         // [1, NH]
    const int* __restrict__ seq,            // [NB, NS]
    float* __restrict__ out)                // [NB, NITEM]
{
    __shared__ float sLDS[NS];   // raw scores
    __shared__ float pLDS[NS];   // softmax probs

    const int b = blockIdx.x;
    const int tid = (int)threadIdx.x;
    const int lane = tid & 63;
    const int warp = __builtin_amdgcn_readfirstlane(tid >> 6);

    // Hoist the scatter indices (wave 0 only needs them, tiny coalesced load).
    int item = (tid < NS) ? seq[b * NS + tid] : 0;

    // ---- phase 1: scores (s split across the 4 waves) ----
    float ur[NH];
    {
        const float* urow = Ur + lane * NH;
        #pragma unroll
        for (int h = 0; h < NH; h += 4) {
            float4 u = *(const float4*)(urow + h);
            ur[h] = u.x; ur[h + 1] = u.y; ur[h + 2] = u.z; ur[h + 3] = u.w;
        }
    }
    float lm = 0.f;
    {
        const float* lrow = last_memory + b * NH;   // wave-uniform
        const float* wrow = Wr + lane * NH;
        #pragma unroll
        for (int h = 0; h < NH; h += 4) {
            float4 w = *(const float4*)(wrow + h);
            float4 l = *(const float4*)(lrow + h);
            lm += w.x * l.x + w.y * l.y + w.z * l.z + w.w * l.w;
        }
    }
    const float vw = Vr_w[lane];
    const float* am = all_memory + (long long)b * (NS * NH);

    for (int s = warp; s < NS; s += 4) {
        const float* arow = am + s * NH;            // wave-uniform
        float v0 = 0.f, v1 = 0.f, v2 = 0.f, v3 = 0.f;
        #pragma unroll
        for (int h = 0; h < NH; h += 4) {
            float4 a = *(const float4*)(arow + h);
            v0 += a.x * ur[h];
            v1 += a.y * ur[h + 1];
            v2 += a.z * ur[h + 2];
            v3 += a.w * ur[h + 3];
        }
        // Vr_b dropped: constant score shift cancels in softmax.
        float t = tanhf(lm + ((v0 + v1) + (v2 + v3))) * vw;
        #pragma unroll
        for (int off = 32; off >= 1; off >>= 1)
            t += __shfl_xor(t, off, 64);
        if (lane == 0) sLDS[s] = t;
    }

    __syncthreads();   // only small input loads outstanding -> cheap drain

    // ---- phase 3a: wave 0 softmax (overlaps waves 1-3 store issue) ----
    if (warp == 0) {
        float sc = (lane < NS) ? sLDS[lane] : -INFINITY;
        float m = sc;
        #pragma unroll
        for (int off = 32; off >= 1; off >>= 1)
            m = fmaxf(m, __shfl_xor(m, off, 64));
        float e = (lane < NS) ? expf(sc - m) : 0.f;
        float d = e;
        #pragma unroll
        for (int off = 32; off >= 1; off >>= 1)
            d += __shfl_xor(d, off, 64);
        if (lane < NS) pLDS[lane] = e / d;
    }

    // ---- phase 3b: zero own row (plain stores -> L2-allocating) ----
    f4* orow4 = (f4*)(out + (long long)b * NITEM);
    const f4 z = (f4)(0.0f);
    for (int i = tid; i < ROW4; i += 256)
        orow4[i] = z;

    __syncthreads();   // the store drain — this is the BW-bound work itself

    // ---- phase 4: scatter (wave 0; pLDS written & read by wave 0) ----
    if (tid < NS)
        atomicAdd(out + (long long)b * NITEM + item, pLDS[tid]);
}

extern "C" void kernel_launch(void* const* d_in, const int* in_sizes, int n_in,
                              void* d_out, int out_size, void* d_ws, size_t ws_size,
                              hipStream_t stream) {
    const float* all_memory  = (const float*)d_in[0];
    const float* last_memory = (const float*)d_in[1];
    const float* Wr          = (const float*)d_in[2];
    const float* Ur          = (const float*)d_in[3];
    const float* Vr_w        = (const float*)d_in[4];
    // d_in[5] = Vr_b: constant shift of all scores, cancels in softmax.
    const int*   seq         = (const int*)d_in[6];
    float* out = (float*)d_out;

    fused_row<<<NB, 256, 0, stream>>>(all_memory, last_memory, Wr, Ur, Vr_w,
                                      seq, out);
}

// Round 5
// 249.712 us; speedup vs baseline: 1.0202x; 1.0202x over previous
//
#include <hip/hip_runtime.h>
#include <math.h>

#define NB 4096
#define NS 50
#define NH 64
#define NITEM 40000

// ---------- kernel 1: probs ----------
// One wave per row b (4 waves/block). Lane i owns output-dim i with Ur[i,:]
// in 64 VGPRs; all_memory row addresses are wave-uniform -> one cache line
// per load broadcast across the wave. Lane s ends up with score[b,s];
// softmax is done fully in-wave via shfl. probs -> d_ws.
__global__ __launch_bounds__(256) void probs_k(
    const float* __restrict__ all_memory,   // [NB, NS, NH]
    const float* __restrict__ last_memory,  // [NB, NH]
    const float* __restrict__ Wr,           // [NH, NH]
    const float* __restrict__ Ur,           // [NH, NH]
    const float* __restrict__ Vr_w,         // [1, NH]
    float* __restrict__ probs)              // [NB, NS] (workspace)
{
    const int lane = (int)threadIdx.x & 63;
    const int warp = __builtin_amdgcn_readfirstlane((int)threadIdx.x >> 6);
    const int b = blockIdx.x * 4 + warp;    // wave-uniform

    float ur[NH];
    {
        const float* urow = Ur + lane * NH;
        #pragma unroll
        for (int h = 0; h < NH; h += 4) {
            float4 u = *(const float4*)(urow + h);
            ur[h] = u.x; ur[h + 1] = u.y; ur[h + 2] = u.z; ur[h + 3] = u.w;
        }
    }
    float lm = 0.f;
    {
        const float* lrow = last_memory + b * NH;   // wave-uniform
        const float* wrow = Wr + lane * NH;
        #pragma unroll
        for (int h = 0; h < NH; h += 4) {
            float4 w = *(const float4*)(wrow + h);
            float4 l = *(const float4*)(lrow + h);
            lm += w.x * l.x + w.y * l.y + w.z * l.z + w.w * l.w;
        }
    }
    const float vw = Vr_w[lane];
    const float* am = all_memory + (long long)b * (NS * NH);

    float myscore = 0.f;
    for (int s = 0; s < NS; ++s) {
        const float* arow = am + s * NH;            // wave-uniform
        float v0 = 0.f, v1 = 0.f, v2 = 0.f, v3 = 0.f;
        #pragma unroll
        for (int h = 0; h < NH; h += 4) {
            float4 a = *(const float4*)(arow + h);
            v0 += a.x * ur[h];
            v1 += a.y * ur[h + 1];
            v2 += a.z * ur[h + 2];
            v3 += a.w * ur[h + 3];
        }
        // Vr_b dropped: constant score shift cancels in softmax.
        float t = tanhf(lm + ((v0 + v1) + (v2 + v3))) * vw;
        #pragma unroll
        for (int off = 32; off >= 1; off >>= 1)
            t += __shfl_xor(t, off, 64);
        myscore = (lane == s) ? t : myscore;
    }

    // in-wave softmax over lanes 0..NS-1
    float sc = (lane < NS) ? myscore : -INFINITY;
    float m = sc;
    #pragma unroll
    for (int off = 32; off >= 1; off >>= 1)
        m = fmaxf(m, __shfl_xor(m, off, 64));
    float e = (lane < NS) ? expf(sc - m) : 0.f;
    float d = e;
    #pragma unroll
    for (int off = 32; off >= 1; off >>= 1)
        d += __shfl_xor(d, off, 64);
    if (lane < NS)
        probs[b * NS + lane] = e / d;
}

// ---------- kernel 3: scatter ----------
// One thread per (b, s). atomicAdd accumulates duplicate items exactly like
// the reference's .at[].add.
__global__ __launch_bounds__(256) void scatter_k(
    const float* __restrict__ probs,
    const int* __restrict__ seq,
    float* __restrict__ out)
{
    int t = blockIdx.x * 256 + threadIdx.x;
    if (t >= NB * NS) return;
    int b = t / NS;
    float p = probs[t];
    int item = seq[t];
    atomicAdd(out + (long long)b * NITEM + item, p);
}

extern "C" void kernel_launch(void* const* d_in, const int* in_sizes, int n_in,
                              void* d_out, int out_size, void* d_ws, size_t ws_size,
                              hipStream_t stream) {
    const float* all_memory  = (const float*)d_in[0];
    const float* last_memory = (const float*)d_in[1];
    const float* Wr          = (const float*)d_in[2];
    const float* Ur          = (const float*)d_in[3];
    const float* Vr_w        = (const float*)d_in[4];
    // d_in[5] = Vr_b: constant shift of all scores, cancels in softmax.
    const int*   seq         = (const int*)d_in[6];
    float* out   = (float*)d_out;
    float* probs = (float*)d_ws;   // NB*NS floats = 819,200 B

    // 1. probs (independent of the memset; runs first)
    probs_k<<<NB / 4, 256, 0, stream>>>(all_memory, last_memory, Wr, Ur, Vr_w,
                                        probs);

    // 2. zero the 655 MB output via the runtime's tuned fill path
    //    (stream-ordered, graph-capturable memset node; measured 6.6 TB/s)
    hipMemsetAsync(d_out, 0, (size_t)out_size * sizeof(float), stream);

    // 3. scatter probs onto the zeroed rows
    scatter_k<<<(NB * NS + 255) / 256, 256, 0, stream>>>(probs, seq, out);
}